// Round 6
// baseline (319.532 us; speedup 1.0000x reference)
//
#include <hip/hip_runtime.h>
#include <hip/hip_bf16.h>
#include <math.h>

#define HIDDEN 1024
#define INTER  1408
#define NEXP   8
#define NTOK   2048
#define KSPLIT_LEN 704   // INTER/2

typedef short s16x8 __attribute__((ext_vector_type(8)));   // 8 bf16 MFMA operand
typedef float f32x4 __attribute__((ext_vector_type(4)));   // MFMA accumulator

static __device__ __forceinline__ short f2b(float f) {
  union { float f; unsigned u; } v; v.f = f;
  unsigned u = v.u;
  unsigned r = (u + 0x7FFFu + ((u >> 16) & 1u)) >> 16;   // RNE
  return (short)r;
}

// pack 2 fp32 -> u32 of 2 bf16 (RNE), low short = a. v_cvt_pk_bf16_f32.
static __device__ __forceinline__ unsigned cvtpk2(float a, float b) {
  __hip_bfloat162 h = __float22bfloat162_rn(make_float2(a, b));
  union { __hip_bfloat162 h; unsigned u; } v; v.h = h;
  return v.u;
}

// ---------------------------------------------------------------------------
// In-staging transpose-convert of a fp32 weight panel (replaces the wconv
// pre-pass; saves 138 MB of HBM round-trip traffic).
// Wave wv covers k-octet wv of the 32-k window. Lane (li=lane&31, hb2=lane>>5):
//   4 x float4 loads: rows k + 4*hb2 + j (j=0..3), cols n0+4li..+3
//     (each load instr = two contiguous 512B row segments)
//   cvt_pk packs k-pairs per column -> lane holds 8B half-chunks of 4 columns
//   (h=0: k0-3, h=1: k4-7); one shfl_xor(32) exchange completes two full 16B
//   chunks per lane (columns 4li+2*hb2, +1) -> ds_write_b128 into the SAME
//   XOR-swizzled LDS layout the MFMA fragment reads already use.
// ---------------------------------------------------------------------------
static __device__ __forceinline__ void stage_b_fp32(
    const float* __restrict__ p, int stride, int hb2,
    uint4& c0, uint4& c1)
{
  float4 t0 = *(const float4*)(p);
  float4 t1 = *(const float4*)(p + stride);
  float4 t2 = *(const float4*)(p + 2 * (size_t)stride);
  float4 t3 = *(const float4*)(p + 3 * (size_t)stride);
  unsigned p0 = cvtpk2(t0.x, t1.x), p1 = cvtpk2(t2.x, t3.x);   // col 0
  unsigned p2 = cvtpk2(t0.y, t1.y), p3 = cvtpk2(t2.y, t3.y);   // col 1
  unsigned p4 = cvtpk2(t0.z, t1.z), p5 = cvtpk2(t2.z, t3.z);   // col 2
  unsigned p6 = cvtpk2(t0.w, t1.w), p7 = cvtpk2(t2.w, t3.w);   // col 3
  // h=0 sends cols 2,3 (its k0-3); h=1 sends cols 0,1 (its k4-7)
  unsigned s0 = hb2 ? p0 : p4, s1 = hb2 ? p1 : p5;
  unsigned s2 = hb2 ? p2 : p6, s3 = hb2 ? p3 : p7;
  unsigned r0 = (unsigned)__shfl_xor((int)s0, 32);
  unsigned r1 = (unsigned)__shfl_xor((int)s1, 32);
  unsigned r2 = (unsigned)__shfl_xor((int)s2, 32);
  unsigned r3 = (unsigned)__shfl_xor((int)s3, 32);
  if (hb2 == 0) {
    c0 = make_uint4(p0, p1, r0, r1);   // row 4li+0: k0-7
    c1 = make_uint4(p2, p3, r2, r3);   // row 4li+1
  } else {
    c0 = make_uint4(r0, r1, p4, p5);   // row 4li+2
    c1 = make_uint4(r2, r3, p6, p7);   // row 4li+3
  }
}

// ---------------------------------------------------------------------------
// Router: one wave per token, fp32 exact; also emits xb (bf16 copy of x).
// ---------------------------------------------------------------------------
__global__ __launch_bounds__(256) void router_choice(
    const float* __restrict__ x, const float* __restrict__ rw,
    int* __restrict__ ce, float2* __restrict__ cw, short* __restrict__ xb)
{
  int wave = threadIdx.x >> 6;
  int lane = threadIdx.x & 63;
  int t = blockIdx.x * 4 + wave;
  if (t >= NTOK) return;
  const float* xt = x + (size_t)t * HIDDEN;
  float xr[16];
#pragma unroll
  for (int i = 0; i < 16; ++i) xr[i] = xt[lane + 64 * i];

  short* xo = xb + (size_t)t * HIDDEN;
#pragma unroll
  for (int i = 0; i < 16; ++i) xo[lane + 64 * i] = f2b(xr[i]);

  float logits[NEXP];
#pragma unroll
  for (int e = 0; e < NEXP; ++e) {
    const float* w = rw + e * HIDDEN;
    float acc = 0.f;
#pragma unroll
    for (int i = 0; i < 16; ++i) acc = fmaf(xr[i], w[lane + 64 * i], acc);
#pragma unroll
    for (int off = 32; off > 0; off >>= 1) acc += __shfl_xor(acc, off);
    logits[e] = acc;
  }
  if (lane == 0) {
    float mx = logits[0];
#pragma unroll
    for (int e = 1; e < NEXP; ++e) mx = fmaxf(mx, logits[e]);
    float p[NEXP];
#pragma unroll
    for (int e = 0; e < NEXP; ++e) p[e] = expf(logits[e] - mx);
    int i0 = 0;
#pragma unroll
    for (int e = 1; e < NEXP; ++e) if (p[e] > p[i0]) i0 = e;
    int i1 = (i0 == 0) ? 1 : 0;
#pragma unroll
    for (int e = 0; e < NEXP; ++e) { if (e != i0 && p[e] > p[i1]) i1 = e; }
    float denom = p[i0] + p[i1];
    ce[t] = i0 | (i1 << 8);
    cw[t] = make_float2(p[i0] / denom, p[i1] / denom);
  }
}

// ---------------------------------------------------------------------------
// Router phase 2: deterministic compaction per expert.
// ---------------------------------------------------------------------------
__global__ __launch_bounds__(256) void build_lists(
    const int* __restrict__ ce, const float2* __restrict__ cw,
    int* __restrict__ counts, int* __restrict__ base,
    int* __restrict__ tok_list, float* __restrict__ w_list)
{
  int e = blockIdx.x;          // 0..7
  int tid = threadIdx.x;       // each thread owns tokens [8*tid, 8*tid+8)
  __shared__ int hall[256][8];
  __shared__ int hsum[8];
  __shared__ int scan[256];

  int cloc[8];
  int h[8] = {0,0,0,0,0,0,0,0};
  int myc = 0;
#pragma unroll
  for (int j = 0; j < 8; ++j) {
    int c = ce[tid * 8 + j];
    cloc[j] = c;
    int e0 = c & 255, e1 = (c >> 8) & 255;
    h[e0]++; h[e1]++;
    myc += (e0 == e) + (e1 == e);
  }
#pragma unroll
  for (int k = 0; k < 8; ++k) hall[tid][k] = h[k];
  scan[tid] = myc;
  __syncthreads();

  if (tid < 8) {
    int s = 0;
    for (int i = 0; i < 256; ++i) s += hall[i][tid];
    hsum[tid] = s;
  }
  int v = myc;
  for (int off = 1; off < 256; off <<= 1) {
    int prev = (tid >= off) ? scan[tid - off] : 0;
    __syncthreads();
    v = v + prev;
    scan[tid] = v;
    __syncthreads();
  }
  int pos = v - myc;

  if (tid == 0) {
    int b = 0;
    for (int k = 0; k < e; ++k) b += hsum[k];
    base[e] = b;
    counts[e] = hsum[e];
  }

#pragma unroll
  for (int j = 0; j < 8; ++j) {
    int t = tid * 8 + j;
    int c = cloc[j];
    int e0 = c & 255, e1 = (c >> 8) & 255;
    if (e0 == e) {
      float2 w = cw[t];
      tok_list[e * NTOK + pos] = t;
      w_list[e * NTOK + pos] = w.x;
      pos++;
    } else if (e1 == e) {
      float2 w = cw[t];
      tok_list[e * NTOK + pos] = t | (1 << 16);
      w_list[e * NTOK + pos] = w.y;
      pos++;
    }
  }
}

// ---------------------------------------------------------------------------
// Phase A: H = silu(X@Wg)*(X@Wu). Tile M=128 N=128 BK=32, 4 waves (2x2),
// B staged DIRECTLY from fp32 wg/wu (in-register transpose-convert).
// Fragment reads / MFMA / epilogue identical to the r4-verified kernel.
// ---------------------------------------------------------------------------
__global__ __launch_bounds__(256, 2) void gateup_mfma(
    const short* __restrict__ xb, const float* __restrict__ wg,
    const float* __restrict__ wu,
    const int* __restrict__ counts, const int* __restrict__ base,
    const int* __restrict__ tok_list, short* __restrict__ hbuf)
{
  // grid = 8 xcd * 16 m * 11 g-hi = 1408; all m-blocks of one (e,n) panel
  // share an XCD -> fp32 panel re-reads are L2-local.
  int id = blockIdx.x;
  int xcd = id & 7;
  int rest = id >> 3;
  int mslot = rest & 15;
  int g = (rest >> 4) * 8 + xcd;
  int e = g / 11;
  int n0 = (g - e * 11) * 128;
  int cnt = counts[e];
  int m0 = mslot * 128;
  if (m0 >= cnt) return;

  __shared__ short As[128 * 32];
  __shared__ short Bg[128 * 32];
  __shared__ short Bu[128 * 32];
  __shared__ int toks[128];

  int tid = threadIdx.x;
  if (tid < 128) {
    int r = m0 + tid;
    toks[tid] = tok_list[e * NTOK + (r < cnt ? r : cnt - 1)] & 0xFFFF;
  }
  __syncthreads();

  // ---- A staging (bf16 xb), unchanged
  int sr = tid >> 1, ha = tid & 1;
  int key = (sr >> 1) & 3;
  int pair = ((2 * ha) ^ key) >> 1;
  int sw = (key & 1) * 8;
  const short* gA = xb + (size_t)toks[sr] * HIDDEN + pair * 16;
  short* wA0 = &As[sr * 32 + ha * 16 + sw];
  short* wA1 = &As[sr * 32 + ha * 16 + (8 - sw)];

  // ---- B staging from fp32
  int wv = tid >> 6, lane = tid & 63;
  int li = lane & 31, hb2 = lane >> 5;
  size_t wbase = (size_t)e * (HIDDEN * INTER)
               + (size_t)(8 * wv + 4 * hb2) * INTER + n0 + 4 * li;
  const float* gG = wg + wbase;
  const float* gU = wu + wbase;
  int rn0 = 4 * li + 2 * hb2, rn1 = rn0 + 1;
  int ph = wv ^ ((rn0 >> 1) & 3);              // rn0>>1 == rn1>>1
  short* wG0 = &Bg[rn0 * 32 + ph * 8];
  short* wG1 = &Bg[rn1 * 32 + ph * 8];
  short* wU0 = &Bu[rn0 * 32 + ph * 8];
  short* wU1 = &Bu[rn1 * 32 + ph * 8];

  int wm = wv & 1, wn = wv >> 1;
  int q = lane >> 4, ml = lane & 15;
  int chk = q ^ ((ml >> 1) & 3);
  const short* ard = &As[(wm * 64 + ml) * 32 + chk * 8];
  const short* grd = &Bg[(wn * 64 + ml) * 32 + chk * 8];
  const short* urd = &Bu[(wn * 64 + ml) * 32 + chk * 8];

  f32x4 accg[4][4], accu[4][4];
#pragma unroll
  for (int i = 0; i < 4; ++i)
#pragma unroll
    for (int j = 0; j < 4; ++j) { accg[i][j] = (f32x4)0.f; accu[i][j] = (f32x4)0.f; }

  s16x8 a0 = *(const s16x8*)(gA);     s16x8 a1 = *(const s16x8*)(gA + 8);
  uint4 g0c, g1c, u0c, u1c;
  stage_b_fp32(gG, INTER, hb2, g0c, g1c);
  stage_b_fp32(gU, INTER, hb2, u0c, u1c);

  for (int k0 = 0; k0 < HIDDEN; k0 += 32) {
    __syncthreads();
    *(s16x8*)wA0 = a0; *(s16x8*)wA1 = a1;
    *(uint4*)wG0 = g0c; *(uint4*)wG1 = g1c;
    *(uint4*)wU0 = u0c; *(uint4*)wU1 = u1c;
    __syncthreads();

    int kn = (k0 + 32) & (HIDDEN - 1);
    a0 = *(const s16x8*)(gA + kn);  a1 = *(const s16x8*)(gA + kn + 8);
    stage_b_fp32(gG + (size_t)kn * INTER, INTER, hb2, g0c, g1c);
    stage_b_fp32(gU + (size_t)kn * INTER, INTER, hb2, u0c, u1c);

    s16x8 af[4], gf[4], uf[4];
#pragma unroll
    for (int i = 0; i < 4; ++i) af[i] = *(const s16x8*)(ard + i * 16 * 32);
#pragma unroll
    for (int j = 0; j < 4; ++j) {
      gf[j] = *(const s16x8*)(grd + j * 16 * 32);
      uf[j] = *(const s16x8*)(urd + j * 16 * 32);
    }
#pragma unroll
    for (int i = 0; i < 4; ++i)
#pragma unroll
      for (int j = 0; j < 4; ++j) {
        accg[i][j] = __builtin_amdgcn_mfma_f32_16x16x32_bf16(af[i], gf[j], accg[i][j], 0, 0, 0);
        accu[i][j] = __builtin_amdgcn_mfma_f32_16x16x32_bf16(af[i], uf[j], accu[i][j], 0, 0, 0);
      }
  }

  int hb = base[e];
#pragma unroll
  for (int i = 0; i < 4; ++i)
#pragma unroll
    for (int ii = 0; ii < 4; ++ii) {
      int r = m0 + wm * 64 + i * 16 + q * 4 + ii;
      if (r < cnt) {
        short* hp = hbuf + (size_t)(hb + r) * INTER + n0 + wn * 64 + ml;
#pragma unroll
        for (int j = 0; j < 4; ++j) {
          float gg = accg[i][j][ii], uu = accu[i][j][ii];
          float hh = (gg / (1.f + __expf(-gg))) * uu;
          hp[j * 16] = f2b(hh);
        }
      }
    }
}

// ---------------------------------------------------------------------------
// Phase B: Y = H @ Wd, K-split x2; B staged directly from fp32 wd.
// ---------------------------------------------------------------------------
__global__ __launch_bounds__(256, 3) void down_mfma(
    const short* __restrict__ hbuf, const float* __restrict__ wd,
    const int* __restrict__ counts, const int* __restrict__ base,
    const int* __restrict__ tok_list, const float* __restrict__ w_list,
    float* __restrict__ ybuf)
{
  // grid = 8 xcd * 16 m * 16 g-hi = 2048; g = (e,ks,n)
  int id = blockIdx.x;
  int xcd = id & 7;
  int rest = id >> 3;
  int mslot = rest & 15;
  int g = (rest >> 4) * 8 + xcd;
  int e = g >> 4;
  int ks = (g >> 3) & 1;
  int n0 = (g & 7) * 128;
  int cnt = counts[e];
  int m0 = mslot * 128;
  if (m0 >= cnt) return;

  __shared__ short As[128 * 32];
  __shared__ short Bs[128 * 32];

  int tid = threadIdx.x;
  int hb = base[e];
  int kbeg = ks * KSPLIT_LEN, kend = kbeg + KSPLIT_LEN;

  // ---- A staging (bf16 hbuf), unchanged
  int sr = tid >> 1, ha = tid & 1;
  int key = (sr >> 1) & 3;
  int pair = ((2 * ha) ^ key) >> 1;
  int sw = (key & 1) * 8;
  int ra = m0 + sr; if (ra >= cnt) ra = cnt - 1;
  const short* gA = hbuf + (size_t)(hb + ra) * INTER + pair * 16;
  short* wA0 = &As[sr * 32 + ha * 16 + sw];
  short* wA1 = &As[sr * 32 + ha * 16 + (8 - sw)];

  // ---- B staging from fp32 wd [k(INTER)][n(HIDDEN)]
  int wv = tid >> 6, lane = tid & 63;
  int li = lane & 31, hb2 = lane >> 5;
  const float* gB = wd + (size_t)e * (HIDDEN * INTER)
                  + (size_t)(8 * wv + 4 * hb2) * HIDDEN + n0 + 4 * li;
  int rn0 = 4 * li + 2 * hb2, rn1 = rn0 + 1;
  int ph = wv ^ ((rn0 >> 1) & 3);
  short* wB0 = &Bs[rn0 * 32 + ph * 8];
  short* wB1 = &Bs[rn1 * 32 + ph * 8];

  int wm = wv & 1, wn = wv >> 1;
  int q = lane >> 4, ml = lane & 15;
  int chk = q ^ ((ml >> 1) & 3);
  const short* ard = &As[(wm * 64 + ml) * 32 + chk * 8];
  const short* brd = &Bs[(wn * 64 + ml) * 32 + chk * 8];

  f32x4 acc[4][4];
#pragma unroll
  for (int i = 0; i < 4; ++i)
#pragma unroll
    for (int j = 0; j < 4; ++j) acc[i][j] = (f32x4)0.f;

  s16x8 a0 = *(const s16x8*)(gA + kbeg);  s16x8 a1 = *(const s16x8*)(gA + kbeg + 8);
  uint4 b0c, b1c;
  stage_b_fp32(gB + (size_t)kbeg * HIDDEN, HIDDEN, hb2, b0c, b1c);

  for (int k0 = kbeg; k0 < kend; k0 += 32) {
    __syncthreads();
    *(s16x8*)wA0 = a0; *(s16x8*)wA1 = a1;
    *(uint4*)wB0 = b0c; *(uint4*)wB1 = b1c;
    __syncthreads();

    int kn = k0 + 32; if (kn >= kend) kn = kbeg;
    a0 = *(const s16x8*)(gA + kn);  a1 = *(const s16x8*)(gA + kn + 8);
    stage_b_fp32(gB + (size_t)kn * HIDDEN, HIDDEN, hb2, b0c, b1c);

    s16x8 af[4], bf[4];
#pragma unroll
    for (int i = 0; i < 4; ++i) af[i] = *(const s16x8*)(ard + i * 16 * 32);
#pragma unroll
    for (int j = 0; j < 4; ++j) bf[j] = *(const s16x8*)(brd + j * 16 * 32);
#pragma unroll
    for (int i = 0; i < 4; ++i)
#pragma unroll
      for (int j = 0; j < 4; ++j)
        acc[i][j] = __builtin_amdgcn_mfma_f32_16x16x32_bf16(af[i], bf[j], acc[i][j], 0, 0, 0);
  }

#pragma unroll
  for (int i = 0; i < 4; ++i)
#pragma unroll
    for (int ii = 0; ii < 4; ++ii) {
      int r = m0 + wm * 64 + i * 16 + q * 4 + ii;
      if (r < cnt) {
        int ent = tok_list[e * NTOK + r];
        int tok = ent & 0xFFFF, slot = ent >> 16;
        float wgt = w_list[e * NTOK + r];
        float* yp = ybuf + ((size_t)(slot * 2 + ks) * NTOK + tok) * HIDDEN
                    + n0 + wn * 64 + ml;
#pragma unroll
        for (int j = 0; j < 4; ++j)
          yp[j * 16] = acc[i][j][ii] * wgt;
      }
    }
}

// ---------------------------------------------------------------------------
// out = sum of 4 ybuf slabs
// ---------------------------------------------------------------------------
__global__ __launch_bounds__(256) void combine_kernel(
    const float* __restrict__ ybuf, float* __restrict__ out)
{
  size_t i = (size_t)blockIdx.x * 256 + threadIdx.x;
  const size_t S = (size_t)NTOK * HIDDEN / 4;
  float4 a = ((const float4*)ybuf)[i];
  float4 b = ((const float4*)ybuf)[i + S];
  float4 c = ((const float4*)ybuf)[i + 2 * S];
  float4 d = ((const float4*)ybuf)[i + 3 * S];
  float4 o;
  o.x = (a.x + b.x) + (c.x + d.x);
  o.y = (a.y + b.y) + (c.y + d.y);
  o.z = (a.z + b.z) + (c.z + d.z);
  o.w = (a.w + b.w) + (c.w + d.w);
  ((float4*)out)[i] = o;
}

// ---------------------------------------------------------------------------
// ws layout (bytes):
//   0..32           counts[8]
//   32..64          base[8]
//   64..65600       tok_list[8][2048]
//   65600..131136   w_list[8][2048]
//   131136..139328  ce[2048]
//   139328..155712  cw[2048] float2
//   155712          xb   bf16 [2048][1024]   (4 MB)
//   +4 MB           hbuf bf16 [4096][1408]   (11.5 MB)
//   +11.5 MB        ybuf fp32 [4][2048][1024] (32 MB)
//   total ~48 MB  (weight transpose buffers DELETED)
// ---------------------------------------------------------------------------
extern "C" void kernel_launch(void* const* d_in, const int* in_sizes, int n_in,
                              void* d_out, int out_size, void* d_ws, size_t ws_size,
                              hipStream_t stream)
{
  const float* x  = (const float*)d_in[0];
  const float* rw = (const float*)d_in[1];
  const float* wg = (const float*)d_in[2];
  const float* wu = (const float*)d_in[3];
  const float* wd = (const float*)d_in[4];
  float* out = (float*)d_out;

  char* ws = (char*)d_ws;
  int*    counts   = (int*)(ws);
  int*    base     = (int*)(ws + 32);
  int*    tok_list = (int*)(ws + 64);
  float*  w_list   = (float*)(ws + 64 + NEXP * NTOK * 4);
  size_t off = 64 + 2 * (size_t)NEXP * NTOK * 4;
  int*    ce = (int*)(ws + off);     off += NTOK * 4;
  float2* cw = (float2*)(ws + off);  off += NTOK * 8;
  short* xb   = (short*)(ws + off);  off += (size_t)NTOK * HIDDEN * 2;
  short* hbuf = (short*)(ws + off);  off += (size_t)2 * NTOK * INTER * 2;
  float* ybuf = (float*)(ws + off);

  router_choice<<<NTOK / 4, 256, 0, stream>>>(x, rw, ce, cw, xb);
  build_lists<<<NEXP, 256, 0, stream>>>(ce, cw, counts, base, tok_list, w_list);

  gateup_mfma<<<8 * 16 * 11, 256, 0, stream>>>(xb, wg, wu, counts, base, tok_list, hbuf);
  down_mfma<<<8 * 16 * 16, 256, 0, stream>>>(hbuf, wd, counts, base, tok_list, w_list, ybuf);

  combine_kernel<<<(NTOK * HIDDEN / 4) / 256, 256, 0, stream>>>(ybuf, out);
}